// Round 1
// baseline (266.958 us; speedup 1.0000x reference)
//
#include <hip/hip_runtime.h>
#include <math.h>

// d is fixed at 256 by the problem (asserted from in_sizes in kernel_launch).
#define D 256

__device__ __forceinline__ float wave_reduce_sum(float v) {
#pragma unroll
    for (int off = 32; off > 0; off >>= 1) v += __shfl_xor(v, off);
    return v;
}

// ---------------------------------------------------------------------------
// Kernel A: everything per batch row b.
//   phase 1: y_s = mean_l E_w[pos[b,l]]
//   phase 2: My  = y_s @ M_w.T + M_b
//   phase 3: z   = sum_l e_l * exp(tanh(e_l . My));  z_s = l2norm(z)
//            (global softmax denom S cancels inside l2norm -> skipped)
//   phase 4: logits = z_s @ lin_w.T + lin_b ; p = softmax(logits)
//   phase 5: r_s = l2norm(p @ T_w)
// block = 256 threads = 4 waves; row gathers are float4-per-lane (1KB/wave).
// ---------------------------------------------------------------------------
__global__ __launch_bounds__(256) void abae_main_kernel(
    const int* __restrict__ pos, const float* __restrict__ E_w,
    const float* __restrict__ T_w, const float* __restrict__ M_w,
    const float* __restrict__ M_b, const float* __restrict__ lin_w,
    const float* __restrict__ lin_b, float* __restrict__ r_s,
    float* __restrict__ z_s, int L, int n_asp) {
    const int b    = blockIdx.x;
    const int t    = threadIdx.x;
    const int lane = t & 63;
    const int wv   = t >> 6;
    const int* __restrict__ posb = pos + (size_t)b * L;

    __shared__ float  sy[D];          // y_s, later reused for normalized z_s
    __shared__ float  smy[D];         // My
    __shared__ float4 sred[4][64];    // cross-wave float4 reduction buffer
    __shared__ float  slog[16];       // aspect logits
    __shared__ float  sp[16];         // softmax probs
    __shared__ float  sscal[4];       // scalar cross-wave reduction

    // ---- phase 1: y_s (each wave handles tokens l = wv, wv+4, ...) ----
    float4 acc = make_float4(0.f, 0.f, 0.f, 0.f);
    for (int l = wv; l < L; l += 4) {
        const int idx = posb[l];
        const float4 e4 = ((const float4*)(E_w + (size_t)idx * D))[lane];
        acc.x += e4.x; acc.y += e4.y; acc.z += e4.z; acc.w += e4.w;
    }
    sred[wv][lane] = acc;
    __syncthreads();
    if (wv == 0) {
        float4 y  = sred[0][lane];
        const float4 a1 = sred[1][lane], a2 = sred[2][lane], a3 = sred[3][lane];
        const float invL = 1.f / (float)L;
        y.x = (y.x + a1.x + a2.x + a3.x) * invL;
        y.y = (y.y + a1.y + a2.y + a3.y) * invL;
        y.z = (y.z + a1.z + a2.z + a3.z) * invL;
        y.w = (y.w + a1.w + a2.w + a3.w) * invL;
        ((float4*)sy)[lane] = y;
    }
    __syncthreads();

    // ---- phase 2: My[t] = M_b[t] + sum_d y[d] * M_w[t,d] ----
    float m = M_b[t];
    const float4* __restrict__ mwrow = (const float4*)(M_w + (size_t)t * D);
#pragma unroll 8
    for (int k = 0; k < D / 4; ++k) {
        const float4 v = mwrow[k];
        m += sy[4 * k + 0] * v.x + sy[4 * k + 1] * v.y +
             sy[4 * k + 2] * v.z + sy[4 * k + 3] * v.w;
    }
    smy[t] = m;
    __syncthreads();

    // ---- phase 3: z = sum_l e_l * exp(tanh(e_l . My)) ----
    const float4 my4 = ((const float4*)smy)[lane];
    float4 zacc = make_float4(0.f, 0.f, 0.f, 0.f);
    for (int l = wv; l < L; l += 4) {
        const int idx = posb[l];
        const float4 e4 = ((const float4*)(E_w + (size_t)idx * D))[lane];
        float p = e4.x * my4.x + e4.y * my4.y + e4.z * my4.z + e4.w * my4.w;
        p = wave_reduce_sum(p);                 // all lanes get the dot
        const float w = expf(tanhf(p));         // un-normalized attention wt
        zacc.x += e4.x * w; zacc.y += e4.y * w;
        zacc.z += e4.z * w; zacc.w += e4.w * w;
    }
    sred[wv][lane] = zacc;
    __syncthreads();
    if (wv == 0) {
        float4 z  = sred[0][lane];
        const float4 a1 = sred[1][lane], a2 = sred[2][lane], a3 = sred[3][lane];
        z.x += a1.x + a2.x + a3.x;
        z.y += a1.y + a2.y + a3.y;
        z.z += a1.z + a2.z + a3.z;
        z.w += a1.w + a2.w + a3.w;
        float ss = z.x * z.x + z.y * z.y + z.z * z.z + z.w * z.w;
        ss = wave_reduce_sum(ss);
        const float inv = 1.f / fmaxf(sqrtf(ss), 1e-12f);
        z.x *= inv; z.y *= inv; z.z *= inv; z.w *= inv;
        ((float4*)(z_s + (size_t)b * D))[lane] = z;  // output 1: z_s
        ((float4*)sy)[lane] = z;                     // reuse sy := z_s
    }
    __syncthreads();

    // ---- phase 4: aspect logits + softmax ----
    const float4 z4 = ((const float4*)sy)[lane];
    for (int a = wv; a < n_asp; a += 4) {
        const float4 w4 = ((const float4*)(lin_w + (size_t)a * D))[lane];
        float p = z4.x * w4.x + z4.y * w4.y + z4.z * w4.z + z4.w * w4.w;
        p = wave_reduce_sum(p);
        if (lane == 0) slog[a] = p + lin_b[a];
    }
    __syncthreads();
    if (t == 0) {
        float mx = -1e30f;
        for (int a = 0; a < n_asp; ++a) mx = fmaxf(mx, slog[a]);
        float s = 0.f;
        for (int a = 0; a < n_asp; ++a) {
            const float e = expf(slog[a] - mx);
            sp[a] = e; s += e;
        }
        const float invs = 1.f / s;
        for (int a = 0; a < n_asp; ++a) sp[a] *= invs;
    }
    __syncthreads();

    // ---- phase 5: r_s = l2norm(p @ T_w) ----
    float r = 0.f;
    for (int a = 0; a < n_asp; ++a) r += sp[a] * T_w[(size_t)a * D + t];
    float sq = wave_reduce_sum(r * r);
    if (lane == 0) sscal[wv] = sq;
    __syncthreads();
    const float tot = sscal[0] + sscal[1] + sscal[2] + sscal[3];
    const float inv = 1.f / fmaxf(sqrtf(tot), 1e-12f);
    r_s[(size_t)b * D + t] = r * inv;                 // output 0: r_s
}

// ---------------------------------------------------------------------------
// Kernel B: z_n[b,m] = l2norm(mean_l E_w[negs[b,m,l]]).  One block per (b,m).
// This is the bandwidth long pole: B*M*L = 512k row gathers (512 MB) from a
// 102 MB table that is fully Infinity-Cache resident.
// ---------------------------------------------------------------------------
__global__ __launch_bounds__(256) void abae_negs_kernel(
    const int* __restrict__ negs, const float* __restrict__ E_w,
    float* __restrict__ z_n, int L) {
    const int bm   = blockIdx.x;
    const int t    = threadIdx.x;
    const int lane = t & 63;
    const int wv   = t >> 6;
    const int* __restrict__ idxp = negs + (size_t)bm * L;

    float4 acc = make_float4(0.f, 0.f, 0.f, 0.f);
    for (int l = wv; l < L; l += 4) {
        const int idx = idxp[l];
        const float4 e4 = ((const float4*)(E_w + (size_t)idx * D))[lane];
        acc.x += e4.x; acc.y += e4.y; acc.z += e4.z; acc.w += e4.w;
    }
    __shared__ float4 sred[4][64];
    sred[wv][lane] = acc;
    __syncthreads();
    if (wv == 0) {
        float4 z  = sred[0][lane];
        const float4 a1 = sred[1][lane], a2 = sred[2][lane], a3 = sred[3][lane];
        const float invL = 1.f / (float)L;
        z.x = (z.x + a1.x + a2.x + a3.x) * invL;
        z.y = (z.y + a1.y + a2.y + a3.y) * invL;
        z.z = (z.z + a1.z + a2.z + a3.z) * invL;
        z.w = (z.w + a1.w + a2.w + a3.w) * invL;
        float ss = z.x * z.x + z.y * z.y + z.z * z.z + z.w * z.w;
        ss = wave_reduce_sum(ss);
        const float inv = 1.f / fmaxf(sqrtf(ss), 1e-12f);
        z.x *= inv; z.y *= inv; z.z *= inv; z.w *= inv;
        ((float4*)(z_n + (size_t)bm * D))[lane] = z;
    }
}

extern "C" void kernel_launch(void* const* d_in, const int* in_sizes, int n_in,
                              void* d_out, int out_size, void* d_ws, size_t ws_size,
                              hipStream_t stream) {
    const int*   pos   = (const int*)d_in[0];
    const int*   negs  = (const int*)d_in[1];
    const float* E_w   = (const float*)d_in[2];
    const float* T_w   = (const float*)d_in[3];
    const float* M_w   = (const float*)d_in[4];
    const float* M_b   = (const float*)d_in[5];
    const float* lin_w = (const float*)d_in[6];
    const float* lin_b = (const float*)d_in[7];
    float* out = (float*)d_out;

    const int d     = in_sizes[5];                 // 256 (M_b)
    const int n_asp = in_sizes[7];                 // 14  (lin_b)
    const int M     = in_sizes[1] / in_sizes[0];   // 10
    const int B     = out_size / (d * (2 + M));    // 512
    const int L     = in_sizes[0] / B;             // 100
    (void)d; (void)n_in; (void)d_ws; (void)ws_size;

    float* r_s = out;                              // [B, d]
    float* z_s = out + (size_t)B * d;              // [B, d]
    float* z_n = out + (size_t)2 * B * d;          // [B, M, d]

    // Long pole first; both kernels are independent.
    abae_negs_kernel<<<B * M, 256, 0, stream>>>(negs, E_w, z_n, L);
    abae_main_kernel<<<B, 256, 0, stream>>>(pos, E_w, T_w, M_w, M_b, lin_w,
                                            lin_b, r_s, z_s, L, n_asp);
}

// Round 2
// 253.035 us; speedup vs baseline: 1.0550x; 1.0550x over previous
//
#include <hip/hip_runtime.h>
#include <math.h>

#define D 256
#define LMAX 100   // L = 100 in this problem; LDS staging sized for it

__device__ __forceinline__ float wave_reduce_sum(float v) {
#pragma unroll
    for (int off = 32; off > 0; off >>= 1) v += __shfl_xor(v, off);
    return v;
}

// ---------------------------------------------------------------------------
// Kernel A: everything per batch row b. 512 threads = 8 waves.
// Token embeddings are staged once into LDS (100 rows x 1KB = 100 KB), so the
// attention pass (phase 3) never touches global memory.
//   phase 1: stage e_l to LDS, y_s = mean_l e_l
//   phase 2: My = y_s @ M_w.T + M_b
//   phase 3: z = sum_l e_l * exp(tanh(e_l . My)); z_s = l2norm(z)
//            (global softmax denom cancels inside l2norm -> skipped)
//   phase 4: p = softmax(z_s @ lin_w.T + lin_b)
//   phase 5: r_s = l2norm(p @ T_w)
// ---------------------------------------------------------------------------
__global__ __launch_bounds__(512) void abae_main_kernel(
    const int* __restrict__ pos, const float* __restrict__ E_w,
    const float* __restrict__ T_w, const float* __restrict__ M_w,
    const float* __restrict__ M_b, const float* __restrict__ lin_w,
    const float* __restrict__ lin_b, float* __restrict__ r_s,
    float* __restrict__ z_s, int L, int n_asp) {
    const int b    = blockIdx.x;
    const int t    = threadIdx.x;
    const int lane = t & 63;
    const int wv   = t >> 6;          // 0..7
    const int NW   = 8;
    const int* __restrict__ posb = pos + (size_t)b * L;

    __shared__ float  se[LMAX * D];   // staged embeddings, row-contiguous
    __shared__ float  sy[D];          // y_s, later reused for z_s
    __shared__ float  smy[D];         // My
    __shared__ float4 sred[8][64];    // cross-wave float4 reduction
    __shared__ float  slog[16];
    __shared__ float  sp[16];
    __shared__ float  sscal[8];

    const int C  = (L + NW - 1) / NW;         // tokens per wave (13)
    const int s0 = wv * C;
    const int e0 = min(L, s0 + C);

    // ---- phase 1: gather rows -> LDS (+ y_s partial), 4 loads in flight ----
    float4 acc = make_float4(0.f, 0.f, 0.f, 0.f);
    int l = s0;
    for (; l + 3 < e0; l += 4) {
        const int i0 = posb[l], i1 = posb[l + 1], i2 = posb[l + 2], i3 = posb[l + 3];
        const float4 a0 = ((const float4*)(E_w + (size_t)i0 * D))[lane];
        const float4 a1 = ((const float4*)(E_w + (size_t)i1 * D))[lane];
        const float4 a2 = ((const float4*)(E_w + (size_t)i2 * D))[lane];
        const float4 a3 = ((const float4*)(E_w + (size_t)i3 * D))[lane];
        ((float4*)se)[(l + 0) * 64 + lane] = a0;
        ((float4*)se)[(l + 1) * 64 + lane] = a1;
        ((float4*)se)[(l + 2) * 64 + lane] = a2;
        ((float4*)se)[(l + 3) * 64 + lane] = a3;
        acc.x += a0.x + a1.x + a2.x + a3.x;
        acc.y += a0.y + a1.y + a2.y + a3.y;
        acc.z += a0.z + a1.z + a2.z + a3.z;
        acc.w += a0.w + a1.w + a2.w + a3.w;
    }
    for (; l < e0; ++l) {
        const int idx = posb[l];
        const float4 a0 = ((const float4*)(E_w + (size_t)idx * D))[lane];
        ((float4*)se)[l * 64 + lane] = a0;
        acc.x += a0.x; acc.y += a0.y; acc.z += a0.z; acc.w += a0.w;
    }
    sred[wv][lane] = acc;
    __syncthreads();
    if (wv == 0) {
        float4 y = sred[0][lane];
#pragma unroll
        for (int w = 1; w < 8; ++w) {
            const float4 a = sred[w][lane];
            y.x += a.x; y.y += a.y; y.z += a.z; y.w += a.w;
        }
        const float invL = 1.f / (float)L;
        y.x *= invL; y.y *= invL; y.z *= invL; y.w *= invL;
        ((float4*)sy)[lane] = y;
    }
    __syncthreads();

    // ---- phase 2: My[t] = M_b[t] + sum_d y[d] * M_w[t,d] ----
    if (t < D) {
        float m = M_b[t];
        const float4* __restrict__ mwrow = (const float4*)(M_w + (size_t)t * D);
#pragma unroll 8
        for (int k = 0; k < D / 4; ++k) {
            const float4 v = mwrow[k];
            m += sy[4 * k + 0] * v.x + sy[4 * k + 1] * v.y +
                 sy[4 * k + 2] * v.z + sy[4 * k + 3] * v.w;
        }
        smy[t] = m;
    }
    __syncthreads();

    // ---- phase 3: attention-weighted sum, all from LDS, 2 tokens in flight --
    const float4 my4 = ((const float4*)smy)[lane];
    float4 zacc = make_float4(0.f, 0.f, 0.f, 0.f);
    l = s0;
    for (; l + 1 < e0; l += 2) {
        const float4 ea = ((const float4*)se)[(l + 0) * 64 + lane];
        const float4 eb = ((const float4*)se)[(l + 1) * 64 + lane];
        float pa = ea.x * my4.x + ea.y * my4.y + ea.z * my4.z + ea.w * my4.w;
        float pb = eb.x * my4.x + eb.y * my4.y + eb.z * my4.z + eb.w * my4.w;
#pragma unroll
        for (int off = 32; off > 0; off >>= 1) {
            pa += __shfl_xor(pa, off);
            pb += __shfl_xor(pb, off);
        }
        const float wa = expf(tanhf(pa));
        const float wb = expf(tanhf(pb));
        zacc.x += ea.x * wa + eb.x * wb;
        zacc.y += ea.y * wa + eb.y * wb;
        zacc.z += ea.z * wa + eb.z * wb;
        zacc.w += ea.w * wa + eb.w * wb;
    }
    for (; l < e0; ++l) {
        const float4 ea = ((const float4*)se)[l * 64 + lane];
        float pa = ea.x * my4.x + ea.y * my4.y + ea.z * my4.z + ea.w * my4.w;
        pa = wave_reduce_sum(pa);
        const float wa = expf(tanhf(pa));
        zacc.x += ea.x * wa; zacc.y += ea.y * wa;
        zacc.z += ea.z * wa; zacc.w += ea.w * wa;
    }
    sred[wv][lane] = zacc;
    __syncthreads();
    if (wv == 0) {
        float4 z = sred[0][lane];
#pragma unroll
        for (int w = 1; w < 8; ++w) {
            const float4 a = sred[w][lane];
            z.x += a.x; z.y += a.y; z.z += a.z; z.w += a.w;
        }
        float ss = z.x * z.x + z.y * z.y + z.z * z.z + z.w * z.w;
        ss = wave_reduce_sum(ss);
        const float inv = 1.f / fmaxf(sqrtf(ss), 1e-12f);
        z.x *= inv; z.y *= inv; z.z *= inv; z.w *= inv;
        ((float4*)(z_s + (size_t)b * D))[lane] = z;   // output 1: z_s
        ((float4*)sy)[lane] = z;                      // reuse sy := z_s
    }
    __syncthreads();

    // ---- phase 4: aspect logits + softmax ----
    const float4 z4 = ((const float4*)sy)[lane];
    for (int a = wv; a < n_asp; a += NW) {
        const float4 w4 = ((const float4*)(lin_w + (size_t)a * D))[lane];
        float p = z4.x * w4.x + z4.y * w4.y + z4.z * w4.z + z4.w * w4.w;
        p = wave_reduce_sum(p);
        if (lane == 0) slog[a] = p + lin_b[a];
    }
    __syncthreads();
    if (t == 0) {
        float mx = -1e30f;
        for (int a = 0; a < n_asp; ++a) mx = fmaxf(mx, slog[a]);
        float s = 0.f;
        for (int a = 0; a < n_asp; ++a) {
            const float e = expf(slog[a] - mx);
            sp[a] = e; s += e;
        }
        const float invs = 1.f / s;
        for (int a = 0; a < n_asp; ++a) sp[a] *= invs;
    }
    __syncthreads();

    // ---- phase 5: r_s = l2norm(p @ T_w)  (threads 0..255 only) ----
    float r = 0.f;
    if (t < D) {
        for (int a = 0; a < n_asp; ++a) r += sp[a] * T_w[(size_t)a * D + t];
    }
    float sq = wave_reduce_sum(r * r);
    if (lane == 0) sscal[wv] = sq;
    __syncthreads();
    if (t < D) {
        const float tot = sscal[0] + sscal[1] + sscal[2] + sscal[3];
        const float inv = 1.f / fmaxf(sqrtf(tot), 1e-12f);
        r_s[(size_t)b * D + t] = r * inv;             // output 0: r_s
    }
}

// ---------------------------------------------------------------------------
// Kernel B: z_n[b,m] = l2norm(mean_l E_w[negs[b,m,l]]).  One block per (b,m),
// 5-way unrolled gathers so each lane keeps 5 float4 loads in flight
// (round 1 had VGPR=12 -> ~1 outstanding load -> latency-bound at 36% HBM).
// ---------------------------------------------------------------------------
__global__ __launch_bounds__(256) void abae_negs_kernel(
    const int* __restrict__ negs, const float* __restrict__ E_w,
    float* __restrict__ z_n, int L) {
    const int bm   = blockIdx.x;
    const int t    = threadIdx.x;
    const int lane = t & 63;
    const int wv   = t >> 6;
    const int* __restrict__ idxp = negs + (size_t)bm * L;

    const int C  = (L + 3) / 4;       // tokens per wave (25)
    const int s0 = wv * C;
    const int e0 = min(L, s0 + C);

    float4 acc = make_float4(0.f, 0.f, 0.f, 0.f);
    int l = s0;
    for (; l + 5 <= e0; l += 5) {
        const int i0 = idxp[l], i1 = idxp[l + 1], i2 = idxp[l + 2],
                  i3 = idxp[l + 3], i4 = idxp[l + 4];
        const float4 v0 = ((const float4*)(E_w + (size_t)i0 * D))[lane];
        const float4 v1 = ((const float4*)(E_w + (size_t)i1 * D))[lane];
        const float4 v2 = ((const float4*)(E_w + (size_t)i2 * D))[lane];
        const float4 v3 = ((const float4*)(E_w + (size_t)i3 * D))[lane];
        const float4 v4 = ((const float4*)(E_w + (size_t)i4 * D))[lane];
        acc.x += v0.x + v1.x + v2.x + v3.x + v4.x;
        acc.y += v0.y + v1.y + v2.y + v3.y + v4.y;
        acc.z += v0.z + v1.z + v2.z + v3.z + v4.z;
        acc.w += v0.w + v1.w + v2.w + v3.w + v4.w;
    }
    for (; l < e0; ++l) {
        const int idx = idxp[l];
        const float4 v = ((const float4*)(E_w + (size_t)idx * D))[lane];
        acc.x += v.x; acc.y += v.y; acc.z += v.z; acc.w += v.w;
    }

    __shared__ float4 sred[4][64];
    sred[wv][lane] = acc;
    __syncthreads();
    if (wv == 0) {
        float4 z  = sred[0][lane];
        const float4 a1 = sred[1][lane], a2 = sred[2][lane], a3 = sred[3][lane];
        const float invL = 1.f / (float)L;
        z.x = (z.x + a1.x + a2.x + a3.x) * invL;
        z.y = (z.y + a1.y + a2.y + a3.y) * invL;
        z.z = (z.z + a1.z + a2.z + a3.z) * invL;
        z.w = (z.w + a1.w + a2.w + a3.w) * invL;
        float ss = z.x * z.x + z.y * z.y + z.z * z.z + z.w * z.w;
        ss = wave_reduce_sum(ss);
        const float inv = 1.f / fmaxf(sqrtf(ss), 1e-12f);
        z.x *= inv; z.y *= inv; z.z *= inv; z.w *= inv;
        ((float4*)(z_n + (size_t)bm * D))[lane] = z;
    }
}

extern "C" void kernel_launch(void* const* d_in, const int* in_sizes, int n_in,
                              void* d_out, int out_size, void* d_ws, size_t ws_size,
                              hipStream_t stream) {
    const int*   pos   = (const int*)d_in[0];
    const int*   negs  = (const int*)d_in[1];
    const float* E_w   = (const float*)d_in[2];
    const float* T_w   = (const float*)d_in[3];
    const float* M_w   = (const float*)d_in[4];
    const float* M_b   = (const float*)d_in[5];
    const float* lin_w = (const float*)d_in[6];
    const float* lin_b = (const float*)d_in[7];
    float* out = (float*)d_out;

    const int d     = in_sizes[5];                 // 256 (M_b)
    const int n_asp = in_sizes[7];                 // 14  (lin_b)
    const int M     = in_sizes[1] / in_sizes[0];   // 10
    const int B     = out_size / (d * (2 + M));    // 512
    const int L     = in_sizes[0] / B;             // 100
    (void)d; (void)n_in; (void)d_ws; (void)ws_size;

    float* r_s = out;                              // [B, d]
    float* z_s = out + (size_t)B * d;              // [B, d]
    float* z_n = out + (size_t)2 * B * d;          // [B, M, d]

    abae_negs_kernel<<<B * M, 256, 0, stream>>>(negs, E_w, z_n, L);
    abae_main_kernel<<<B, 512, 0, stream>>>(pos, E_w, T_w, M_w, M_b, lin_w,
                                            lin_b, r_s, z_s, L, n_asp);
}

// Round 3
// 227.966 us; speedup vs baseline: 1.1710x; 1.1100x over previous
//
#include <hip/hip_runtime.h>
#include <math.h>

#define D 256

__device__ __forceinline__ float wave_reduce_sum(float v) {
#pragma unroll
    for (int off = 32; off > 0; off >>= 1) v += __shfl_xor(v, off);
    return v;
}

// ---------------------------------------------------------------------------
// Fused kernel, 256 threads = 4 waves per block.
//   blocks [0, B)            : "main" path for batch row b = blockIdx.x
//   blocks [B, B + B*M)      : "negs" path for pair bm = blockIdx.x - B
// Rationale (R2 counters): negs is bandwidth-bound at ~3 TB/s on the L2-miss
// path (FETCH 249 MB, VALUBusy 8%) — its latency slack is free execution room
// for the main path's compute phases. Fusing removes the serial ~80 us main
// kernel almost entirely.
// ---------------------------------------------------------------------------
__global__ __launch_bounds__(256) void abae_fused_kernel(
    const int* __restrict__ pos, const int* __restrict__ negs,
    const float* __restrict__ E_w, const float* __restrict__ T_w,
    const float* __restrict__ M_w, const float* __restrict__ M_b,
    const float* __restrict__ lin_w, const float* __restrict__ lin_b,
    float* __restrict__ r_s, float* __restrict__ z_s, float* __restrict__ z_n,
    int B, int L, int n_asp) {
    const int t    = threadIdx.x;
    const int lane = t & 63;
    const int wv   = t >> 6;            // 0..3

    __shared__ float4 sred[4][64];
    __shared__ float  sy[D];            // y_s, later z_s
    __shared__ float  smy[D];           // My
    __shared__ float  slog[16];
    __shared__ float  sp[16];
    __shared__ float  sscal[4];

    if (blockIdx.x >= B) {
        // ================= negs path: z_n[bm] = l2norm(mean_l E_w[negs]) ====
        const int bm = blockIdx.x - B;
        const int* __restrict__ idxp = negs + (size_t)bm * L;
        const int C  = (L + 3) / 4;     // 25 tokens per wave
        const int s0 = wv * C;
        const int e0 = min(L, s0 + C);

        float4 acc = make_float4(0.f, 0.f, 0.f, 0.f);
        int l = s0;
        for (; l + 5 <= e0; l += 5) {   // 5 gathers in flight per lane
            const int i0 = idxp[l], i1 = idxp[l + 1], i2 = idxp[l + 2],
                      i3 = idxp[l + 3], i4 = idxp[l + 4];
            const float4 v0 = ((const float4*)(E_w + (size_t)i0 * D))[lane];
            const float4 v1 = ((const float4*)(E_w + (size_t)i1 * D))[lane];
            const float4 v2 = ((const float4*)(E_w + (size_t)i2 * D))[lane];
            const float4 v3 = ((const float4*)(E_w + (size_t)i3 * D))[lane];
            const float4 v4 = ((const float4*)(E_w + (size_t)i4 * D))[lane];
            acc.x += v0.x + v1.x + v2.x + v3.x + v4.x;
            acc.y += v0.y + v1.y + v2.y + v3.y + v4.y;
            acc.z += v0.z + v1.z + v2.z + v3.z + v4.z;
            acc.w += v0.w + v1.w + v2.w + v3.w + v4.w;
        }
        for (; l < e0; ++l) {
            const float4 v = ((const float4*)(E_w + (size_t)idxp[l] * D))[lane];
            acc.x += v.x; acc.y += v.y; acc.z += v.z; acc.w += v.w;
        }
        sred[wv][lane] = acc;
        __syncthreads();
        if (wv == 0) {
            float4 z  = sred[0][lane];
            const float4 a1 = sred[1][lane], a2 = sred[2][lane], a3 = sred[3][lane];
            const float invL = 1.f / (float)L;
            z.x = (z.x + a1.x + a2.x + a3.x) * invL;
            z.y = (z.y + a1.y + a2.y + a3.y) * invL;
            z.z = (z.z + a1.z + a2.z + a3.z) * invL;
            z.w = (z.w + a1.w + a2.w + a3.w) * invL;
            float ss = z.x * z.x + z.y * z.y + z.z * z.z + z.w * z.w;
            ss = wave_reduce_sum(ss);
            const float inv = 1.f / fmaxf(sqrtf(ss), 1e-12f);
            z.x *= inv; z.y *= inv; z.z *= inv; z.w *= inv;
            ((float4*)(z_n + (size_t)bm * D))[lane] = z;
        }
        return;
    }

    // ==================== main path: batch row b ============================
    const int b = blockIdx.x;
    const int* __restrict__ posb = pos + (size_t)b * L;
    const int C  = (L + 3) / 4;         // 25 tokens per wave
    const int s0 = wv * C;
    const int e0 = min(L, s0 + C);

    // ---- phase 1: y_s = mean_l E_w[pos[b,l]], 4 gathers in flight ----
    float4 acc = make_float4(0.f, 0.f, 0.f, 0.f);
    int l = s0;
    for (; l + 4 <= e0; l += 4) {
        const int i0 = posb[l], i1 = posb[l + 1], i2 = posb[l + 2], i3 = posb[l + 3];
        const float4 v0 = ((const float4*)(E_w + (size_t)i0 * D))[lane];
        const float4 v1 = ((const float4*)(E_w + (size_t)i1 * D))[lane];
        const float4 v2 = ((const float4*)(E_w + (size_t)i2 * D))[lane];
        const float4 v3 = ((const float4*)(E_w + (size_t)i3 * D))[lane];
        acc.x += v0.x + v1.x + v2.x + v3.x;
        acc.y += v0.y + v1.y + v2.y + v3.y;
        acc.z += v0.z + v1.z + v2.z + v3.z;
        acc.w += v0.w + v1.w + v2.w + v3.w;
    }
    for (; l < e0; ++l) {
        const float4 v = ((const float4*)(E_w + (size_t)posb[l] * D))[lane];
        acc.x += v.x; acc.y += v.y; acc.z += v.z; acc.w += v.w;
    }
    sred[wv][lane] = acc;
    __syncthreads();
    if (wv == 0) {
        float4 y  = sred[0][lane];
        const float4 a1 = sred[1][lane], a2 = sred[2][lane], a3 = sred[3][lane];
        const float invL = 1.f / (float)L;
        y.x = (y.x + a1.x + a2.x + a3.x) * invL;
        y.y = (y.y + a1.y + a2.y + a3.y) * invL;
        y.z = (y.z + a1.z + a2.z + a3.z) * invL;
        y.w = (y.w + a1.w + a2.w + a3.w) * invL;
        ((float4*)sy)[lane] = y;
    }
    __syncthreads();

    // ---- phase 2: My[r] = M_b[r] + M_w[r,:] . y_s  — wave-per-row, one
    // coalesced 1KB load per row (64 lanes x 16B == full row), shuffle-reduce,
    // 4 rows in flight per wave. Fixes R2's 64-distinct-lines-per-instr TA
    // divergence.
    {
        const float4 y4 = ((const float4*)sy)[lane];
        for (int r0 = wv * 64; r0 < wv * 64 + 64; r0 += 4) {
            const float4 m0 = ((const float4*)(M_w + (size_t)(r0 + 0) * D))[lane];
            const float4 m1 = ((const float4*)(M_w + (size_t)(r0 + 1) * D))[lane];
            const float4 m2 = ((const float4*)(M_w + (size_t)(r0 + 2) * D))[lane];
            const float4 m3 = ((const float4*)(M_w + (size_t)(r0 + 3) * D))[lane];
            float p0 = m0.x * y4.x + m0.y * y4.y + m0.z * y4.z + m0.w * y4.w;
            float p1 = m1.x * y4.x + m1.y * y4.y + m1.z * y4.z + m1.w * y4.w;
            float p2 = m2.x * y4.x + m2.y * y4.y + m2.z * y4.z + m2.w * y4.w;
            float p3 = m3.x * y4.x + m3.y * y4.y + m3.z * y4.z + m3.w * y4.w;
#pragma unroll
            for (int off = 32; off > 0; off >>= 1) {
                p0 += __shfl_xor(p0, off);
                p1 += __shfl_xor(p1, off);
                p2 += __shfl_xor(p2, off);
                p3 += __shfl_xor(p3, off);
            }
            if (lane == 0) {
                smy[r0 + 0] = p0 + M_b[r0 + 0];
                smy[r0 + 1] = p1 + M_b[r0 + 1];
                smy[r0 + 2] = p2 + M_b[r0 + 2];
                smy[r0 + 3] = p3 + M_b[r0 + 3];
            }
        }
    }
    __syncthreads();

    // ---- phase 3: z = sum_l e_l * exp(tanh(e_l . My)); rows are L2-warm ----
    const float4 my4 = ((const float4*)smy)[lane];
    float4 zacc = make_float4(0.f, 0.f, 0.f, 0.f);
    l = s0;
    for (; l + 1 < e0; l += 2) {
        const float4 ea = ((const float4*)(E_w + (size_t)posb[l] * D))[lane];
        const float4 eb = ((const float4*)(E_w + (size_t)posb[l + 1] * D))[lane];
        float pa = ea.x * my4.x + ea.y * my4.y + ea.z * my4.z + ea.w * my4.w;
        float pb = eb.x * my4.x + eb.y * my4.y + eb.z * my4.z + eb.w * my4.w;
#pragma unroll
        for (int off = 32; off > 0; off >>= 1) {
            pa += __shfl_xor(pa, off);
            pb += __shfl_xor(pb, off);
        }
        const float wa = expf(tanhf(pa));
        const float wb = expf(tanhf(pb));
        zacc.x += ea.x * wa + eb.x * wb;
        zacc.y += ea.y * wa + eb.y * wb;
        zacc.z += ea.z * wa + eb.z * wb;
        zacc.w += ea.w * wa + eb.w * wb;
    }
    for (; l < e0; ++l) {
        const float4 ea = ((const float4*)(E_w + (size_t)posb[l] * D))[lane];
        float pa = ea.x * my4.x + ea.y * my4.y + ea.z * my4.z + ea.w * my4.w;
        pa = wave_reduce_sum(pa);
        const float wa = expf(tanhf(pa));
        zacc.x += ea.x * wa; zacc.y += ea.y * wa;
        zacc.z += ea.z * wa; zacc.w += ea.w * wa;
    }
    sred[wv][lane] = zacc;
    __syncthreads();
    if (wv == 0) {
        float4 z  = sred[0][lane];
        const float4 a1 = sred[1][lane], a2 = sred[2][lane], a3 = sred[3][lane];
        z.x += a1.x + a2.x + a3.x;
        z.y += a1.y + a2.y + a3.y;
        z.z += a1.z + a2.z + a3.z;
        z.w += a1.w + a2.w + a3.w;
        float ss = z.x * z.x + z.y * z.y + z.z * z.z + z.w * z.w;
        ss = wave_reduce_sum(ss);
        const float inv = 1.f / fmaxf(sqrtf(ss), 1e-12f);
        z.x *= inv; z.y *= inv; z.z *= inv; z.w *= inv;
        ((float4*)(z_s + (size_t)b * D))[lane] = z;   // output 1: z_s
        ((float4*)sy)[lane] = z;                      // sy := z_s
    }
    __syncthreads();

    // ---- phase 4: p = softmax(z_s @ lin_w.T + lin_b) ----
    const float4 z4 = ((const float4*)sy)[lane];
    for (int a = wv; a < n_asp; a += 4) {
        const float4 w4 = ((const float4*)(lin_w + (size_t)a * D))[lane];
        float p = z4.x * w4.x + z4.y * w4.y + z4.z * w4.z + z4.w * w4.w;
        p = wave_reduce_sum(p);
        if (lane == 0) slog[a] = p + lin_b[a];
    }
    __syncthreads();
    if (t == 0) {
        float mx = -1e30f;
        for (int a = 0; a < n_asp; ++a) mx = fmaxf(mx, slog[a]);
        float s = 0.f;
        for (int a = 0; a < n_asp; ++a) {
            const float e = expf(slog[a] - mx);
            sp[a] = e; s += e;
        }
        const float invs = 1.f / s;
        for (int a = 0; a < n_asp; ++a) sp[a] *= invs;
    }
    __syncthreads();

    // ---- phase 5: r_s = l2norm(p @ T_w) ----
    float r = 0.f;
    for (int a = 0; a < n_asp; ++a) r += sp[a] * T_w[(size_t)a * D + t];
    const float sq = wave_reduce_sum(r * r);
    if (lane == 0) sscal[wv] = sq;
    __syncthreads();
    const float tot = sscal[0] + sscal[1] + sscal[2] + sscal[3];
    const float inv = 1.f / fmaxf(sqrtf(tot), 1e-12f);
    r_s[(size_t)b * D + t] = r * inv;                 // output 0: r_s
}

extern "C" void kernel_launch(void* const* d_in, const int* in_sizes, int n_in,
                              void* d_out, int out_size, void* d_ws, size_t ws_size,
                              hipStream_t stream) {
    const int*   pos   = (const int*)d_in[0];
    const int*   negs  = (const int*)d_in[1];
    const float* E_w   = (const float*)d_in[2];
    const float* T_w   = (const float*)d_in[3];
    const float* M_w   = (const float*)d_in[4];
    const float* M_b   = (const float*)d_in[5];
    const float* lin_w = (const float*)d_in[6];
    const float* lin_b = (const float*)d_in[7];
    float* out = (float*)d_out;

    const int d     = in_sizes[5];                 // 256 (M_b)
    const int n_asp = in_sizes[7];                 // 14  (lin_b)
    const int M     = in_sizes[1] / in_sizes[0];   // 10
    const int B     = out_size / (d * (2 + M));    // 512
    const int L     = in_sizes[0] / B;             // 100
    (void)d; (void)n_in; (void)d_ws; (void)ws_size;

    float* r_s = out;                              // [B, d]
    float* z_s = out + (size_t)B * d;              // [B, d]
    float* z_n = out + (size_t)2 * B * d;          // [B, M, d]

    abae_fused_kernel<<<B + B * M, 256, 0, stream>>>(
        pos, negs, E_w, T_w, M_w, M_b, lin_w, lin_b, r_s, z_s, z_n, B, L, n_asp);
}